// Round 3
// baseline (2416.536 us; speedup 1.0000x reference)
//
#include <hip/hip_runtime.h>
#include <math.h>
#include <stdint.h>

#define HIDDEN 4096
#define NEXP   64
#define TOKS   64                 // tokens per workgroup
#define KHALF  2048               // 2-way K-split across wave halves
#define KC     64                 // K per staged chunk (per half)
#define NCH    (KHALF / KC)       // 32 chunk-steps
#define RS     68                 // LDS row stride in floats (64 + 4 pad)
#define TILE_W (64 * RS)          // 4352 floats per tile (64 rows)
#define HBUF_W (2 * TILE_W)       // X tile + W tile per half-buffer

// Fused MoE router: fp32 register-tiled GEMM (no fp32 MFMA on CDNA4) + top-2 softmax.
// Grid 256 (=CU count), 512 thr = 8 waves. Halves h=tid>>8 each own K range
// [2048h, 2048h+2048). Within a half: 256 thr, lane tile 4 tok x 4 exp (16 acc).
// Double-buffered LDS, T14 reg-staging (issue-early/write-late), ONE barrier/step.
// W tile kg-XOR-swizzled (mask=row>>2) -> all LDS reads <=2-way conflicts (free).
// X reads: 4-addr 16x broadcast, pure imm-offset addressing (zero per-k VALU).
__global__ __launch_bounds__(512, 1) void router_kernel(
    const float* __restrict__ X,
    const float* __restrict__ W,
    const float* __restrict__ Bv,
    float* __restrict__ out, int nTok)
{
    __shared__ float smem[4 * HBUF_W];   // 139,264 B: [half][buf][Xtile|Wtile]

    const int tid = threadIdx.x;
    const int h   = tid >> 8;        // k-half 0/1
    const int lt  = tid & 255;       // thread id within half
    const int ty  = lt >> 4;         // token-group 0..15 (tokens 4ty..4ty+3)
    const int tx  = lt & 15;         // expert-group 0..15 (experts 4tx..4tx+3)
    const int t0  = blockIdx.x * TOKS;

    // ---- staging: 8 slots/thread = 4 X + 4 W. Slot r: row=(lt>>4)+16r, kg=lt&15.
    // Wave lanes: 4 rows x 16 kg -> 256 B contiguous per row (coalesced).
    const int sr  = lt >> 4;
    const int skg = lt & 15;
    const float* Xg[4]; const float* Wg[4];
    int xw[4], ww[4];
#pragma unroll
    for (int r = 0; r < 4; ++r) {
        const int row = sr + 16 * r;
        Xg[r] = X + (size_t)(t0 + row) * HIDDEN + h * KHALF + skg * 4;
        Wg[r] = W + (size_t)row * HIDDEN + h * KHALF + skg * 4;
        xw[r] = row * RS + skg * 4;                            // X: unswizzled
        ww[r] = row * RS + ((skg ^ ((row >> 2) & 7)) * 4);     // W: kg-XOR swizzle
    }

    float* hb = smem + h * (2 * HBUF_W);   // this half's two buffers

    float acc[4][4];
#pragma unroll
    for (int i = 0; i < 4; ++i)
#pragma unroll
        for (int j = 0; j < 4; ++j) acc[i][j] = 0.0f;

    // prologue: stage chunk 0 into buf 0
    {
        float4 gx[4], gw[4];
#pragma unroll
        for (int r = 0; r < 4; ++r) { gx[r] = *(const float4*)Xg[r]; gw[r] = *(const float4*)Wg[r]; }
        float* xb = hb; float* wb = hb + TILE_W;
#pragma unroll
        for (int r = 0; r < 4; ++r) { *(float4*)&xb[xw[r]] = gx[r]; *(float4*)&wb[ww[r]] = gw[r]; }
    }
    __syncthreads();

    const int mw = tx & 7;   // W read swizzle mask: (row>>2)&7 with row=4tx+j -> tx&7
    for (int c = 0; c < NCH; ++c) {
        // T14 issue-early: next chunk's global loads ride under this chunk's FMAs
        float4 gx[4], gw[4];
        if (c + 1 < NCH) {
#pragma unroll
            for (int r = 0; r < 4; ++r) {
                gx[r] = *(const float4*)(Xg[r] + (c + 1) * KC);
                gw[r] = *(const float4*)(Wg[r] + (c + 1) * KC);
            }
        }
        const float* xl = hb + (c & 1) * HBUF_W + 4 * ty * RS;
        const float* wl = hb + (c & 1) * HBUF_W + TILE_W + 4 * tx * RS;
#pragma unroll
        for (int kg = 0; kg < 16; ++kg) {
            const float* wk = wl + ((kg ^ mw) << 2);       // 2 VALU per kg-group
            const float4 wf0 = *(const float4*)(wk);
            const float4 wf1 = *(const float4*)(wk + RS);
            const float4 wf2 = *(const float4*)(wk + 2 * RS);
            const float4 wf3 = *(const float4*)(wk + 3 * RS);
#pragma unroll
            for (int i = 0; i < 4; ++i) {
                const float4 xf = *(const float4*)(xl + i * RS + 4 * kg);  // pure imm offset
                acc[i][0] = fmaf(xf.x, wf0.x, acc[i][0]);
                acc[i][0] = fmaf(xf.y, wf0.y, acc[i][0]);
                acc[i][0] = fmaf(xf.z, wf0.z, acc[i][0]);
                acc[i][0] = fmaf(xf.w, wf0.w, acc[i][0]);
                acc[i][1] = fmaf(xf.x, wf1.x, acc[i][1]);
                acc[i][1] = fmaf(xf.y, wf1.y, acc[i][1]);
                acc[i][1] = fmaf(xf.z, wf1.z, acc[i][1]);
                acc[i][1] = fmaf(xf.w, wf1.w, acc[i][1]);
                acc[i][2] = fmaf(xf.x, wf2.x, acc[i][2]);
                acc[i][2] = fmaf(xf.y, wf2.y, acc[i][2]);
                acc[i][2] = fmaf(xf.z, wf2.z, acc[i][2]);
                acc[i][2] = fmaf(xf.w, wf2.w, acc[i][2]);
                acc[i][3] = fmaf(xf.x, wf3.x, acc[i][3]);
                acc[i][3] = fmaf(xf.y, wf3.y, acc[i][3]);
                acc[i][3] = fmaf(xf.z, wf3.z, acc[i][3]);
                acc[i][3] = fmaf(xf.w, wf3.w, acc[i][3]);
            }
        }
        // write-late into the other buffer (WAR-safe: last read of it ended
        // before the PREVIOUS barrier)
        if (c + 1 < NCH) {
            float* xb = hb + ((c + 1) & 1) * HBUF_W;
            float* wb = xb + TILE_W;
#pragma unroll
            for (int r = 0; r < 4; ++r) { *(float4*)&xb[xw[r]] = gx[r]; *(float4*)&wb[ww[r]] = gw[r]; }
        }
        __syncthreads();
    }

    // ---- combine K-halves via transposed tile [e][65] (stride 65: conflict-light)
    float* tt = smem;
    if (h == 1) {
#pragma unroll
        for (int i = 0; i < 4; ++i)
#pragma unroll
            for (int j = 0; j < 4; ++j)
                tt[(4 * tx + j) * 65 + 4 * ty + i] = acc[i][j];
    }
    __syncthreads();

    const size_t offSel = (size_t)nTok * 2;
    const size_t offLog = (size_t)nTok * 4;

    if (h == 0) {
        const float4 bj = *(const float4*)(Bv + 4 * tx);
        const float bja[4] = {bj.x, bj.y, bj.z, bj.w};
#pragma unroll
        for (int i = 0; i < 4; ++i)
#pragma unroll
            for (int j = 0; j < 4; ++j)
                acc[i][j] += tt[(4 * tx + j) * 65 + 4 * ty + i] + bja[j];
        // router_logits: coalesced float4 stores (16 lanes cover a 256B row)
#pragma unroll
        for (int i = 0; i < 4; ++i) {
            float* dst = out + offLog + (size_t)(t0 + 4 * ty + i) * NEXP + 4 * tx;
            *(float4*)dst = make_float4(acc[i][0], acc[i][1], acc[i][2], acc[i][3]);
        }
        // final logits back into the transposed tile for the top-2 scan
#pragma unroll
        for (int i = 0; i < 4; ++i)
#pragma unroll
            for (int j = 0; j < 4; ++j)
                tt[(4 * tx + j) * 65 + 4 * ty + i] = acc[i][j];
    }
    __syncthreads();

    // ---- top-2 + softmax: one token per lane; strict > keeps lowest index
    // on ties (jax.lax.top_k semantics). Verified-passing R1 epilogue.
    if (tid < 64) {
        const int t = tid;
        float m1 = -INFINITY, m2 = -INFINITY;
        int i1 = 0, i2 = 0;
#pragma unroll
        for (int e = 0; e < NEXP; ++e) {
            const float v = tt[e * 65 + t];
            if (v > m1)      { m2 = m1; i2 = i1; m1 = v; i1 = e; }
            else if (v > m2) { m2 = v; i2 = e; }
        }
        const float ex  = expf(m2 - m1);
        const float inv = 1.0f / (1.0f + ex);
        *(float2*)(out + (size_t)(t0 + t) * 2)          = make_float2(inv, ex * inv);
        *(float2*)(out + offSel + (size_t)(t0 + t) * 2) = make_float2((float)i1, (float)i2);
    }

    if (blockIdx.x == 0 && tid == 0)
        out[offLog + (size_t)nTok * NEXP] = 0.0f;   // aux_loss
}

extern "C" void kernel_launch(void* const* d_in, const int* in_sizes, int n_in,
                              void* d_out, int out_size, void* d_ws, size_t ws_size,
                              hipStream_t stream)
{
    const float* X  = (const float*)d_in[0];
    const float* W  = (const float*)d_in[1];
    const float* Bv = (const float*)d_in[2];
    float* out = (float*)d_out;
    const int nTok   = in_sizes[0] / HIDDEN;   // 16384
    const int blocks = nTok / TOKS;            // 256
    router_kernel<<<blocks, 512, 0, stream>>>(X, W, Bv, out, nTok);
}

// Round 4
// 172.737 us; speedup vs baseline: 13.9897x; 13.9897x over previous
//
#include <hip/hip_runtime.h>
#include <math.h>
#include <stdint.h>

#define HIDDEN 4096
#define NEXP   64
#define TOKS   64                 // tokens per workgroup
#define KHALF  2048               // 2-way K-split across thread halves
#define KC     64                 // k floats staged per chunk per half
#define NCH    (KHALF / KC)       // 32 chunk-steps
#define PFL    8192               // floats per parity buffer (X 4096 | W 4096)
#define HFL    (2 * PFL)          // floats per half (double-buffered)

// async global->LDS, 16B per lane, linear dest (wave-uniform base + lane*16)
__device__ __forceinline__ void gload_lds16(const float* g, float* l) {
    __builtin_amdgcn_global_load_lds(
        (const __attribute__((address_space(1))) void*)g,
        (__attribute__((address_space(3))) void*)l, 16, 0, 0);
}

// Fused MoE router: fp32 register-tiled GEMM (no fp32 MFMA on CDNA4) + top-2 softmax.
// 256 blocks x 512 thr (8 waves, 2/SIMD). Half h=tid>>8 owns k in [2048h, 2048h+2048).
// Lane tile 4 tok x 4 exp (16 acc). Staging via global_load_lds (ZERO staging VGPRs --
// R2/R3's reg-staging spilled: 5 GB scratch writes). LDS linear [row][64]; bank
// conflicts fixed by swizzling the GLOBAL source: content at kg' = kg ^ ((row>>2)&7).
// Read masks are lane-constant (ty&7 / tx&7): X conflict-free, W 2-way (free).
__global__ __launch_bounds__(512, 2) void router_kernel(
    const float* __restrict__ X,
    const float* __restrict__ W,
    const float* __restrict__ Bv,
    float* __restrict__ out, int nTok)
{
    __shared__ float smem[2 * HFL];    // 131072 B: [half][parity][X|W]

    const int tid = threadIdx.x;
    const int h   = tid >> 8;          // k-half 0/1
    const int wv2 = (tid >> 6) & 3;    // wave within half
    const int l   = tid & 63;
    const int lr  = l >> 4;            // lane row-in-block 0..3
    const int lk  = l & 15;            // lane kg 0..15
    const int lt  = tid & 255;
    const int ty  = lt >> 4;           // token-group 0..15
    const int tx  = lt & 15;           // expert-group 0..15
    const int t0  = blockIdx.x * TOKS;

    // Staging: wave wv2 stages rows [16wv2, 16wv2+16) of both tiles; instr r
    // covers rows 16wv2+4r .. +3 (1 KiB linear LDS). XOR mask (4wv2+r)&7 is
    // lane-uniform per instr; global side reads a permuted-but-complete 256B row.
    const float* Xg[4]; const float* Wg[4];
    int xdo[4], wdo[4];
#pragma unroll
    for (int r = 0; r < 4; ++r) {
        const int row = 16 * wv2 + 4 * r + lr;
        const int msk = (4 * wv2 + r) & 7;
        const int ksw = (lk ^ msk) << 2;
        Xg[r] = X + (size_t)(t0 + row) * HIDDEN + h * KHALF + ksw;
        Wg[r] = W + (size_t)row * HIDDEN + h * KHALF + ksw;
        const int rb = (16 * wv2 + 4 * r) * 64;
        xdo[r] = rb;                // X tile at +0
        wdo[r] = 4096 + rb;         // W tile at +4096
    }
    float* hbase = smem + h * HFL;

    float acc[4][4];
#pragma unroll
    for (int i = 0; i < 4; ++i)
#pragma unroll
        for (int j = 0; j < 4; ++j) acc[i][j] = 0.0f;

    const int mx4 = (ty & 7) << 2;     // X read swizzle (lane-const)
    const int mw4 = (tx & 7) << 2;     // W read swizzle (lane-const)

    // prologue: stage chunk 0 into parity 0
    {
        float* xb = hbase;
#pragma unroll
        for (int r = 0; r < 4; ++r) gload_lds16(Xg[r], xb + xdo[r]);
#pragma unroll
        for (int r = 0; r < 4; ++r) gload_lds16(Wg[r], xb + wdo[r]);
    }
    __syncthreads();

    for (int c = 0; c < NCH; ++c) {
        // issue next chunk's async loads into the other parity buffer;
        // they land under this chunk's 1024 FMAs (drained by the barrier).
        if (c + 1 < NCH) {
            float* xb = hbase + ((c + 1) & 1) * PFL;
            const int ko = (c + 1) * KC;
#pragma unroll
            for (int r = 0; r < 4; ++r) gload_lds16(Xg[r] + ko, xb + xdo[r]);
#pragma unroll
            for (int r = 0; r < 4; ++r) gload_lds16(Wg[r] + ko, xb + wdo[r]);
        }
        const float* xl = hbase + (c & 1) * PFL + 4 * ty * 64;
        const float* wl = hbase + (c & 1) * PFL + 4096 + 4 * tx * 64;
#pragma unroll
        for (int kg = 0; kg < 16; ++kg) {
            const int kxo = (kg << 2) ^ mx4;
            const int kwo = (kg << 2) ^ mw4;
            const float4 wf0 = *(const float4*)(wl + kwo);
            const float4 wf1 = *(const float4*)(wl + 64 + kwo);
            const float4 wf2 = *(const float4*)(wl + 128 + kwo);
            const float4 wf3 = *(const float4*)(wl + 192 + kwo);
#pragma unroll
            for (int i = 0; i < 4; ++i) {
                const float4 xf = *(const float4*)(xl + i * 64 + kxo);
                acc[i][0] = fmaf(xf.x, wf0.x, acc[i][0]);
                acc[i][0] = fmaf(xf.y, wf0.y, acc[i][0]);
                acc[i][0] = fmaf(xf.z, wf0.z, acc[i][0]);
                acc[i][0] = fmaf(xf.w, wf0.w, acc[i][0]);
                acc[i][1] = fmaf(xf.x, wf1.x, acc[i][1]);
                acc[i][1] = fmaf(xf.y, wf1.y, acc[i][1]);
                acc[i][1] = fmaf(xf.z, wf1.z, acc[i][1]);
                acc[i][1] = fmaf(xf.w, wf1.w, acc[i][1]);
                acc[i][2] = fmaf(xf.x, wf2.x, acc[i][2]);
                acc[i][2] = fmaf(xf.y, wf2.y, acc[i][2]);
                acc[i][2] = fmaf(xf.z, wf2.z, acc[i][2]);
                acc[i][2] = fmaf(xf.w, wf2.w, acc[i][2]);
                acc[i][3] = fmaf(xf.x, wf3.x, acc[i][3]);
                acc[i][3] = fmaf(xf.y, wf3.y, acc[i][3]);
                acc[i][3] = fmaf(xf.z, wf3.z, acc[i][3]);
                acc[i][3] = fmaf(xf.w, wf3.w, acc[i][3]);
            }
        }
        __syncthreads();   // drains vmcnt: next parity buffer complete; WAR-safe
    }

    // ---- combine K-halves via transposed tile [e][65] ----
    float* tt = smem;
    if (h == 1) {
#pragma unroll
        for (int i = 0; i < 4; ++i)
#pragma unroll
            for (int j = 0; j < 4; ++j)
                tt[(4 * tx + j) * 65 + 4 * ty + i] = acc[i][j];
    }
    __syncthreads();

    const size_t offSel = (size_t)nTok * 2;
    const size_t offLog = (size_t)nTok * 4;

    if (h == 0) {
        const float4 bj = *(const float4*)(Bv + 4 * tx);
        const float bja[4] = {bj.x, bj.y, bj.z, bj.w};
#pragma unroll
        for (int i = 0; i < 4; ++i)
#pragma unroll
            for (int j = 0; j < 4; ++j)
                acc[i][j] += tt[(4 * tx + j) * 65 + 4 * ty + i] + bja[j];
        // router_logits: coalesced float4 stores (16 lanes cover a 256B row)
#pragma unroll
        for (int i = 0; i < 4; ++i) {
            float* dst = out + offLog + (size_t)(t0 + 4 * ty + i) * NEXP + 4 * tx;
            *(float4*)dst = make_float4(acc[i][0], acc[i][1], acc[i][2], acc[i][3]);
        }
        // final logits back into the transposed tile for the top-2 scan
#pragma unroll
        for (int i = 0; i < 4; ++i)
#pragma unroll
            for (int j = 0; j < 4; ++j)
                tt[(4 * tx + j) * 65 + 4 * ty + i] = acc[i][j];
    }
    __syncthreads();

    // ---- top-2 + softmax: one token per lane; strict > keeps lowest index
    // on ties (jax.lax.top_k semantics). Verified-passing epilogue.
    if (tid < 64) {
        const int t = tid;
        float m1 = -INFINITY, m2 = -INFINITY;
        int i1 = 0, i2 = 0;
#pragma unroll
        for (int e = 0; e < NEXP; ++e) {
            const float v = tt[e * 65 + t];
            if (v > m1)      { m2 = m1; i2 = i1; m1 = v; i1 = e; }
            else if (v > m2) { m2 = v; i2 = e; }
        }
        const float ex  = expf(m2 - m1);
        const float inv = 1.0f / (1.0f + ex);
        *(float2*)(out + (size_t)(t0 + t) * 2)          = make_float2(inv, ex * inv);
        *(float2*)(out + offSel + (size_t)(t0 + t) * 2) = make_float2((float)i1, (float)i2);
    }

    if (blockIdx.x == 0 && tid == 0)
        out[offLog + (size_t)nTok * NEXP] = 0.0f;   // aux_loss
}

extern "C" void kernel_launch(void* const* d_in, const int* in_sizes, int n_in,
                              void* d_out, int out_size, void* d_ws, size_t ws_size,
                              hipStream_t stream)
{
    const float* X  = (const float*)d_in[0];
    const float* W  = (const float*)d_in[1];
    const float* Bv = (const float*)d_in[2];
    float* out = (float*)d_out;
    const int nTok   = in_sizes[0] / HIDDEN;   // 16384
    const int blocks = nTok / TOKS;            // 256
    router_kernel<<<blocks, 512, 0, stream>>>(X, W, Bv, out, nTok);
}

// Round 5
// 157.456 us; speedup vs baseline: 15.3474x; 1.0971x over previous
//
#include <hip/hip_runtime.h>
#include <math.h>
#include <stdint.h>

#define HIDDEN 4096
#define NEXP   64
#define TOKS   64                // tokens per workgroup
#define NWV    8
#define KPW    (HIDDEN / NWV)    // 512: K-slice per wave
#define KC     16                // k floats per staged chunk
#define NCH    (KPW / KC)        // 32 chunks
#define XW_FL  (TOKS * KC)       // 1024 floats per tile (X or W)
#define PAR_FL (2 * XW_FL)       // 2048 floats per parity (X|W)
#define WV_FL  (2 * PAR_FL)      // 4096 floats per wave (double-buffered)
#define TSTR   68                // reduction-tile row stride
#define TILE_F (64 * TSTR)

// async global->LDS, 16B/lane, linear dest (wave-uniform base + lane*16)
__device__ __forceinline__ void gload_lds16(const float* g, float* l) {
    __builtin_amdgcn_global_load_lds(
        (const __attribute__((address_space(1))) void*)g,
        (__attribute__((address_space(3))) void*)l, 16, 0, 0);
}

// Fused MoE router: fp32 register-tiled GEMM (no fp32 MFMA on CDNA4) + top-2.
// 256 blocks x 512 thr. Each wave computes the FULL 64x64 tile over a private
// K-slice of 512 (8x8 acc per lane => LDS-read:FMA = 1:16, half of R4) with
// private double-buffered LDS -> ZERO main-loop barriers; counted vmcnt(8)
// (T4) for parity safety. Staging via global_load_lds (no staging VGPRs;
// R2/R3 reg-staging spilled 5 GB). Source-swizzle chunk^=(row>>3)&3 (rule
// #21 involution) => all LDS reads 2-way max (free, m136). K-partials
// combined by a 3-round LDS tree; R2's verified top-2/softmax epilogue.
__global__ __launch_bounds__(512, 2) void router_kernel(
    const float* __restrict__ X,
    const float* __restrict__ W,
    const float* __restrict__ Bv,
    float* __restrict__ out, int nTok)
{
    __shared__ float smem[NWV * WV_FL];   // 131072 B

    const int tid = threadIdx.x;
    const int wv  = __builtin_amdgcn_readfirstlane(tid >> 6);
    const int l   = tid & 63;
    const int tr  = l >> 3;          // token-group: rows 8tr..8tr+7
    const int ec  = l & 7;           // expert-group: cols 8ec..8ec+7
    const int t0  = blockIdx.x * TOKS;
    const int kb  = wv * KPW;

    // ---- staging: 4 instrs per tile; instr r covers rows 16r..16r+15,
    // lane l -> row 16r+(l>>2), 16B chunk (l&3). Global source pre-swizzled
    // by mask=(row>>3)&3 so the linear LDS dest ends up read-conflict-light.
    const int srow = l >> 2;
    const int schk = l & 3;
    const float* Xg[4]; const float* Wg[4];
#pragma unroll
    for (int r = 0; r < 4; ++r) {
        const int row  = 16 * r + srow;
        const int koff = ((schk ^ ((row >> 3) & 3)) << 2);
        Xg[r] = X + (size_t)(t0 + row) * HIDDEN + kb + koff;
        Wg[r] = W + (size_t)row * HIDDEN + kb + koff;
    }
    float* wb = smem + wv * WV_FL;

    float acc[8][8];
#pragma unroll
    for (int i = 0; i < 8; ++i)
#pragma unroll
        for (int j = 0; j < 8; ++j) acc[i][j] = 0.0f;

    const int mtr = tr & 3;          // X read swizzle mask (lane-const)
    const int mec = ec & 3;          // W read swizzle mask (lane-const)
    const int xln = tr * (8 * KC);   // 8 rows per tr-group
    const int wln = ec * (8 * KC);

    // prologue: stage chunk 0 into parity 0
#pragma unroll
    for (int r = 0; r < 4; ++r) gload_lds16(Xg[r], wb + r * 256);
#pragma unroll
    for (int r = 0; r < 4; ++r) gload_lds16(Wg[r], wb + XW_FL + r * 256);

    for (int c = 0; c < NCH; ++c) {
        if (c + 1 < NCH) {
            float* pb = wb + ((c + 1) & 1) * PAR_FL;
            const int ko = (c + 1) * KC;
#pragma unroll
            for (int r = 0; r < 4; ++r) gload_lds16(Xg[r] + ko, pb + r * 256);
#pragma unroll
            for (int r = 0; r < 4; ++r) gload_lds16(Wg[r] + ko, pb + XW_FL + r * 256);
            // T4: wait for the PREVIOUS 8 loads (current parity); the 8 just
            // issued stay in flight under this chunk's 1024 FMAs.
            asm volatile("s_waitcnt vmcnt(8)" ::: "memory");
        } else {
            asm volatile("s_waitcnt vmcnt(0)" ::: "memory");
        }
        const float* xl = wb + (c & 1) * PAR_FL;
        const float* wl = xl + XW_FL;
#pragma unroll
        for (int kg = 0; kg < 4; ++kg) {
            const int kxo = ((kg ^ mtr) << 2);
            const int kwo = ((kg ^ mec) << 2);
            float4 wf[8];
#pragma unroll
            for (int j = 0; j < 8; ++j)
                wf[j] = *(const float4*)(wl + wln + KC * j + kwo);
#pragma unroll
            for (int i = 0; i < 8; ++i) {
                const float4 xf = *(const float4*)(xl + xln + KC * i + kxo);
#pragma unroll
                for (int j = 0; j < 8; ++j) {
                    acc[i][j] = fmaf(xf.x, wf[j].x, acc[i][j]);
                    acc[i][j] = fmaf(xf.y, wf[j].y, acc[i][j]);
                    acc[i][j] = fmaf(xf.z, wf[j].z, acc[i][j]);
                    acc[i][j] = fmaf(xf.w, wf[j].w, acc[i][j]);
                }
            }
        }
    }

    // ---- cross-wave K-reduction: 3 rounds of pairwise LDS adds (R2-verified)
    __syncthreads();
#pragma unroll
    for (int half = 4; half >= 1; half >>= 1) {
        if (wv >= half && wv < 2 * half) {
            float* tb = &smem[(wv - half) * TILE_F];
#pragma unroll
            for (int i = 0; i < 8; ++i) {
                float* rowp = &tb[(8 * tr + i) * TSTR + 8 * ec];
                *(float4*)rowp       = make_float4(acc[i][0], acc[i][1], acc[i][2], acc[i][3]);
                *(float4*)(rowp + 4) = make_float4(acc[i][4], acc[i][5], acc[i][6], acc[i][7]);
            }
        }
        __syncthreads();
        if (wv < half) {
            float* tb = &smem[wv * TILE_F];
#pragma unroll
            for (int i = 0; i < 8; ++i) {
                float* rowp = &tb[(8 * tr + i) * TSTR + 8 * ec];
                float4 a = *(const float4*)rowp;
                float4 b = *(const float4*)(rowp + 4);
                acc[i][0] += a.x; acc[i][1] += a.y; acc[i][2] += a.z; acc[i][3] += a.w;
                acc[i][4] += b.x; acc[i][5] += b.y; acc[i][6] += b.z; acc[i][7] += b.w;
            }
        }
        __syncthreads();
    }

    // ---- epilogue: wave 0 holds the final 64x64 tile (R2-verified) ----
    if (wv == 0) {
        const size_t offSel = (size_t)nTok * 2;
        const size_t offLog = (size_t)nTok * 4;

        const float4 b0 = *(const float4*)(Bv + 8 * ec);
        const float4 b1 = *(const float4*)(Bv + 8 * ec + 4);
#pragma unroll
        for (int i = 0; i < 8; ++i) {
            acc[i][0] += b0.x; acc[i][1] += b0.y; acc[i][2] += b0.z; acc[i][3] += b0.w;
            acc[i][4] += b1.x; acc[i][5] += b1.y; acc[i][6] += b1.z; acc[i][7] += b1.w;
        }
        // router_logits: 8 ec-lanes cover a 256B row, float4 stores
#pragma unroll
        for (int i = 0; i < 8; ++i) {
            float* dst = out + offLog + (size_t)(t0 + 8 * tr + i) * NEXP + 8 * ec;
            *(float4*)dst       = make_float4(acc[i][0], acc[i][1], acc[i][2], acc[i][3]);
            *(float4*)(dst + 4) = make_float4(acc[i][4], acc[i][5], acc[i][6], acc[i][7]);
        }
        // top-2: per-lane scan of 8 experts, 3-step shfl_xor merge across the
        // 8 ec-lanes. Strict > + lowest-index tie-break (jax top_k semantics).
#pragma unroll
        for (int i = 0; i < 8; ++i) {
            float m1 = acc[i][0]; int i1 = 8 * ec;
            float m2 = -INFINITY; int i2 = 0;
#pragma unroll
            for (int j = 1; j < 8; ++j) {
                const float v = acc[i][j]; const int e = 8 * ec + j;
                if (v > m1)      { m2 = m1; i2 = i1; m1 = v; i1 = e; }
                else if (v > m2) { m2 = v; i2 = e; }
            }
#pragma unroll
            for (int m = 1; m < 8; m <<= 1) {
                const float om1 = __shfl_xor(m1, m);
                const int   oi1 = __shfl_xor(i1, m);
                const float om2 = __shfl_xor(m2, m);
                const int   oi2 = __shfl_xor(i2, m);
                const bool b1 = (om1 > m1) || (om1 == m1 && oi1 < i1);
                const float n1  = b1 ? om1 : m1; const int ni1 = b1 ? oi1 : i1;
                const float c2v = b1 ? m1 : om1; const int c2i = b1 ? i1 : oi1;
                const float c3v = b1 ? om2 : m2; const int c3i = b1 ? oi2 : i2;
                const bool b2 = (c3v > c2v) || (c3v == c2v && c3i < c2i);
                m1 = n1; i1 = ni1;
                m2 = b2 ? c3v : c2v; i2 = b2 ? c3i : c2i;
            }
            if (ec == 0) {
                const float ex  = expf(m2 - m1);
                const float inv = 1.0f / (1.0f + ex);
                const int t = t0 + 8 * tr + i;
                *(float2*)(out + (size_t)t * 2)          = make_float2(inv, ex * inv);
                *(float2*)(out + offSel + (size_t)t * 2) = make_float2((float)i1, (float)i2);
            }
        }
        if (blockIdx.x == 0 && tid == 0)
            out[offLog + (size_t)nTok * NEXP] = 0.0f;   // aux_loss
    }
}

extern "C" void kernel_launch(void* const* d_in, const int* in_sizes, int n_in,
                              void* d_out, int out_size, void* d_ws, size_t ws_size,
                              hipStream_t stream)
{
    const float* X  = (const float*)d_in[0];
    const float* W  = (const float*)d_in[1];
    const float* Bv = (const float*)d_in[2];
    float* out = (float*)d_out;
    const int nTok   = in_sizes[0] / HIDDEN;   // 16384
    const int blocks = nTok / TOKS;            // 256
    router_kernel<<<blocks, 512, 0, stream>>>(X, W, Bv, out, nTok);
}